// Round 1
// baseline (254.033 us; speedup 1.0000x reference)
//
#include <hip/hip_runtime.h>
#include <hip/hip_bf16.h>

#define B_ 4
#define N_ 2048
#define F_ 256
#define H_ 4
#define D_ 64

typedef __attribute__((ext_vector_type(8))) short short8;
typedef __attribute__((ext_vector_type(4))) float f32x4;

__device__ __forceinline__ unsigned short f2bf(float x) {
  unsigned u = __builtin_bit_cast(unsigned, x);
  u = (u + 0x7fffu + ((u >> 16) & 1u)) >> 16;
  return (unsigned short)u;
}

__device__ __forceinline__ f32x4 mfma16(short8 a, short8 b, f32x4 c) {
  return __builtin_amdgcn_mfma_f32_16x16x32_bf16(a, b, c, 0, 0, 0);
}

// ---------------- prep: h->bf16, weights transpose->bf16, adj->bitmask ----------------
__global__ __launch_bounds__(256) void prep_kernel(
    const float* __restrict__ h, const int* __restrict__ adj,
    const float* __restrict__ Wq, const float* __restrict__ Wk,
    const float* __restrict__ Wv, const float* __restrict__ Wo,
    unsigned short* __restrict__ hbf,
    unsigned short* __restrict__ wqt, unsigned short* __restrict__ wkt,
    unsigned short* __restrict__ wvt, unsigned short* __restrict__ wot,
    unsigned* __restrict__ adjp) {
  int bid = blockIdx.x;
  int tid = threadIdx.x;
  if (bid < 2048) {
    // h conversion: 2,097,152 elements, float4 per thread
    int idx = (bid * 256 + tid) * 4;
    float4 v = *(const float4*)(h + idx);
    ushort4 o;
    o.x = f2bf(v.x); o.y = f2bf(v.y); o.z = f2bf(v.z); o.w = f2bf(v.w);
    *(ushort4*)(hbf + idx) = o;
  } else if (bid < 3072) {
    // weight transpose: 4 * 65536 elements
    int t = (bid - 2048) * 256 + tid;
    int w = t >> 16;
    int e = t & 65535;
    int i = e >> 8;      // in-feature
    int o = e & 255;     // out-feature (consecutive threads -> coalesced read)
    const float* W = (w == 0) ? Wq : (w == 1) ? Wk : (w == 2) ? Wv : Wo;
    unsigned short* Wt = (w == 0) ? wqt : (w == 1) ? wkt : (w == 2) ? wvt : wot;
    Wt[o * 256 + i] = f2bf(W[i * 256 + o]);
  } else {
    // adj bit-pack via ballot: 4M elements -> 64K uint64 words
    int lane = tid & 63;
    int wid = (bid - 3072) * 4 + (tid >> 6);   // 0..4095
    unsigned long long* adjp64 = (unsigned long long*)adjp;
    #pragma unroll
    for (int it = 0; it < 16; ++it) {
      int widx = wid * 16 + it;                // 0..65535
      int base = widx * 64 + lane;
      unsigned long long m = __ballot(adj[base] != 0);
      if (lane == 0) adjp64[widx] = m;
    }
  }
}

// ---------------- QKV projection GEMM: [8192,256] x [256,768] ----------------
__global__ __launch_bounds__(256) void qkv_gemm(
    const unsigned short* __restrict__ hbf,
    const unsigned short* __restrict__ wqt, const unsigned short* __restrict__ wkt,
    const unsigned short* __restrict__ wvt,
    unsigned short* __restrict__ qb, unsigned short* __restrict__ kb,
    unsigned short* __restrict__ vtb) {
  int lane = threadIdx.x & 63;
  int wv = threadIdx.x >> 6;
  int g = lane >> 4;
  int c = lane & 15;
  int row16 = blockIdx.x * 64 + wv * 16;
  int colbase = blockIdx.y * 64;
  int which = colbase >> 8;          // 0=Q 1=K 2=V
  int fbase = colbase & 255;
  const unsigned short* wt = (which == 0) ? wqt : (which == 1) ? wkt : wvt;
  int arow = row16 + c;

  f32x4 acc[4];
  #pragma unroll
  for (int cc = 0; cc < 4; ++cc) acc[cc] = (f32x4){0.f, 0.f, 0.f, 0.f};

  for (int k = 0; k < 256; k += 32) {
    short8 a = *(const short8*)(hbf + arow * 256 + k + g * 8);
    #pragma unroll
    for (int cc = 0; cc < 4; ++cc) {
      int col = fbase + cc * 16 + c;
      short8 bfrag = *(const short8*)(wt + col * 256 + k + g * 8);
      acc[cc] = mfma16(a, bfrag, acc[cc]);
    }
  }

  #pragma unroll
  for (int cc = 0; cc < 4; ++cc) {
    #pragma unroll
    for (int r = 0; r < 4; ++r) {
      int row = row16 + g * 4 + r;
      int f = fbase + cc * 16 + c;
      int hh = f >> 6, d = f & 63;
      int bb = row >> 11, n = row & 2047;
      float v = acc[cc][r];
      if (which == 0)
        qb[((bb * H_ + hh) * N_ + n) * D_ + d] = f2bf(v * 0.125f);
      else if (which == 1)
        kb[((bb * H_ + hh) * N_ + n) * D_ + d] = f2bf(v);
      else
        vtb[((bb * H_ + hh) * D_ + d) * N_ + n] = f2bf(v);
    }
  }
}

// ---------------- flash attention with adjacency mask ----------------
__global__ __launch_bounds__(256) void attn_kernel(
    const unsigned short* __restrict__ qb, const unsigned short* __restrict__ kb,
    const unsigned short* __restrict__ vtb, const unsigned* __restrict__ adjp,
    unsigned short* __restrict__ attn_out) {
  __shared__ __align__(16) unsigned short plds[4][32 * 40];
  int lane = threadIdx.x & 63;
  int wv = threadIdx.x >> 6;
  int g = lane >> 4;
  int c = lane & 15;
  int task = blockIdx.x * 4 + wv;     // 0..1023
  int bh = task >> 6;                 // 0..15
  int qt = task & 63;
  int qbase = qt * 32;
  int bb = bh >> 2, hh = bh & 3;
  const unsigned short* Qp = qb + bh * (N_ * D_);
  const unsigned short* Kp = kb + bh * (N_ * D_);
  const unsigned short* Vt = vtb + bh * (D_ * N_);
  unsigned short* myp = plds[wv];

  short8 qf[2][2];
  #pragma unroll
  for (int rt = 0; rt < 2; ++rt)
    #pragma unroll
    for (int dh = 0; dh < 2; ++dh)
      qf[rt][dh] = *(const short8*)(Qp + (qbase + rt * 16 + c) * D_ + dh * 32 + g * 8);

  f32x4 O[2][4];
  float M[2][4], L[2][4];
  #pragma unroll
  for (int rt = 0; rt < 2; ++rt) {
    #pragma unroll
    for (int dt = 0; dt < 4; ++dt) O[rt][dt] = (f32x4){0.f, 0.f, 0.f, 0.f};
    #pragma unroll
    for (int r = 0; r < 4; ++r) { M[rt][r] = -1e9f; L[rt][r] = 0.f; }
  }

  const f32x4 z4 = {0.f, 0.f, 0.f, 0.f};

  for (int mb = 0; mb < N_; mb += 32) {
    int mw = mb >> 5;
    short8 kf[2][2];
    #pragma unroll
    for (int mt = 0; mt < 2; ++mt)
      #pragma unroll
      for (int dh = 0; dh < 2; ++dh)
        kf[mt][dh] = *(const short8*)(Kp + (mb + mt * 16 + c) * D_ + dh * 32 + g * 8);

    f32x4 S[2][2];
    #pragma unroll
    for (int rt = 0; rt < 2; ++rt)
      #pragma unroll
      for (int mt = 0; mt < 2; ++mt) {
        f32x4 s = mfma16(qf[rt][0], kf[mt][0], z4);
        S[rt][mt] = mfma16(qf[rt][1], kf[mt][1], s);
      }

    #pragma unroll
    for (int rt = 0; rt < 2; ++rt) {
      #pragma unroll
      for (int r = 0; r < 4; ++r) {
        int n = qbase + rt * 16 + g * 4 + r;
        unsigned aw = adjp[n * 64 + mw];
        float s0 = ((aw >> c) & 1u) ? S[rt][0][r] : -1e9f;
        float s1 = ((aw >> (c + 16)) & 1u) ? S[rt][1][r] : -1e9f;
        float mx = fmaxf(s0, s1);
        mx = fmaxf(mx, __shfl_xor(mx, 1));
        mx = fmaxf(mx, __shfl_xor(mx, 2));
        mx = fmaxf(mx, __shfl_xor(mx, 4));
        mx = fmaxf(mx, __shfl_xor(mx, 8));
        float Mn = fmaxf(M[rt][r], mx);
        float sc = __expf(M[rt][r] - Mn);
        M[rt][r] = Mn;
        float p0 = __expf(s0 - Mn);
        float p1 = __expf(s1 - Mn);
        float rs = p0 + p1;
        rs += __shfl_xor(rs, 1);
        rs += __shfl_xor(rs, 2);
        rs += __shfl_xor(rs, 4);
        rs += __shfl_xor(rs, 8);
        L[rt][r] = L[rt][r] * sc + rs;
        #pragma unroll
        for (int dt = 0; dt < 4; ++dt) O[rt][dt][r] *= sc;
        int prow = rt * 16 + g * 4 + r;
        myp[prow * 40 + c] = f2bf(p0);
        myp[prow * 40 + 16 + c] = f2bf(p1);
      }
    }

    short8 pa[2];
    #pragma unroll
    for (int rt = 0; rt < 2; ++rt)
      pa[rt] = *(const short8*)(myp + (rt * 16 + c) * 40 + g * 8);

    #pragma unroll
    for (int dt = 0; dt < 4; ++dt) {
      short8 vf = *(const short8*)(Vt + (dt * 16 + c) * N_ + mb + g * 8);
      #pragma unroll
      for (int rt = 0; rt < 2; ++rt)
        O[rt][dt] = mfma16(pa[rt], vf, O[rt][dt]);
    }
  }

  #pragma unroll
  for (int rt = 0; rt < 2; ++rt) {
    #pragma unroll
    for (int r = 0; r < 4; ++r) {
      float inv = 1.0f / L[rt][r];
      int n = qbase + rt * 16 + g * 4 + r;
      #pragma unroll
      for (int dt = 0; dt < 4; ++dt) {
        attn_out[(bb * N_ + n) * F_ + hh * 64 + dt * 16 + c] = f2bf(O[rt][dt][r] * inv);
      }
    }
  }
}

// ---------------- output GEMM + residual + bias ----------------
__global__ __launch_bounds__(256) void out_gemm(
    const unsigned short* __restrict__ ao, const unsigned short* __restrict__ wot,
    const float* __restrict__ h, const float* __restrict__ bo,
    float* __restrict__ out) {
  int lane = threadIdx.x & 63;
  int wv = threadIdx.x >> 6;
  int g = lane >> 4;
  int c = lane & 15;
  int row16 = blockIdx.x * 64 + wv * 16;
  int colb = blockIdx.y * 64;
  int arow = row16 + c;

  f32x4 acc[4];
  #pragma unroll
  for (int cc = 0; cc < 4; ++cc) acc[cc] = (f32x4){0.f, 0.f, 0.f, 0.f};

  for (int k = 0; k < 256; k += 32) {
    short8 a = *(const short8*)(ao + arow * 256 + k + g * 8);
    #pragma unroll
    for (int cc = 0; cc < 4; ++cc) {
      int col = colb + cc * 16 + c;
      short8 bfrag = *(const short8*)(wot + col * 256 + k + g * 8);
      acc[cc] = mfma16(a, bfrag, acc[cc]);
    }
  }

  #pragma unroll
  for (int cc = 0; cc < 4; ++cc) {
    #pragma unroll
    for (int r = 0; r < 4; ++r) {
      int row = row16 + g * 4 + r;
      int col = colb + cc * 16 + c;
      out[row * 256 + col] = h[row * 256 + col] + bo[col] + acc[cc][r];
    }
  }
}

extern "C" void kernel_launch(void* const* d_in, const int* in_sizes, int n_in,
                              void* d_out, int out_size, void* d_ws, size_t ws_size,
                              hipStream_t stream) {
  (void)in_sizes; (void)n_in; (void)out_size; (void)ws_size;
  const float* h  = (const float*)d_in[0];
  const int* adj  = (const int*)d_in[1];
  const float* Wq = (const float*)d_in[2];
  const float* Wk = (const float*)d_in[3];
  const float* Wv = (const float*)d_in[4];
  const float* Wo = (const float*)d_in[5];
  const float* bo = (const float*)d_in[6];
  float* out = (float*)d_out;

  char* ws = (char*)d_ws;
  unsigned short* hbf = (unsigned short*)(ws + 0);          // 4 MB
  unsigned short* wqt = (unsigned short*)(ws + 4194304);    // 128 KB
  unsigned short* wkt = (unsigned short*)(ws + 4325376);    // 128 KB
  unsigned short* wvt = (unsigned short*)(ws + 4456448);    // 128 KB
  unsigned short* wot = (unsigned short*)(ws + 4587520);    // 128 KB
  unsigned*       adjp = (unsigned*)(ws + 4718592);         // 512 KB
  unsigned short* qb  = (unsigned short*)(ws + 5242880);    // 4 MB
  unsigned short* kb  = (unsigned short*)(ws + 9437184);    // 4 MB
  unsigned short* vtb = (unsigned short*)(ws + 13631488);   // 4 MB
  unsigned short* ao  = (unsigned short*)(ws + 17825792);   // 4 MB  (end ~22 MB)

  prep_kernel<<<4096, 256, 0, stream>>>(h, adj, Wq, Wk, Wv, Wo,
                                        hbf, wqt, wkt, wvt, wot, adjp);
  qkv_gemm<<<dim3(128, 12), 256, 0, stream>>>(hbf, wqt, wkt, wvt, qb, kb, vtb);
  attn_kernel<<<256, 256, 0, stream>>>(qb, kb, vtb, adjp, ao);
  out_gemm<<<dim3(128, 4), 256, 0, stream>>>(ao, wot, h, bo, out);
}

// Round 2
// 210.566 us; speedup vs baseline: 1.2064x; 1.2064x over previous
//
#include <hip/hip_runtime.h>
#include <hip/hip_bf16.h>

#define B_ 4
#define N_ 2048
#define F_ 256
#define H_ 4
#define D_ 64

typedef __attribute__((ext_vector_type(8))) short short8;
typedef __attribute__((ext_vector_type(4))) float f32x4;

__device__ __forceinline__ unsigned short f2bf(float x) {
  unsigned u = __builtin_bit_cast(unsigned, x);
  u = (u + 0x7fffu + ((u >> 16) & 1u)) >> 16;
  return (unsigned short)u;
}

__device__ __forceinline__ float bf2f(unsigned short x) {
  unsigned u = ((unsigned)x) << 16;
  return __builtin_bit_cast(float, u);
}

__device__ __forceinline__ f32x4 mfma16(short8 a, short8 b, f32x4 c) {
  return __builtin_amdgcn_mfma_f32_16x16x32_bf16(a, b, c, 0, 0, 0);
}

// ---------------- prep: h->bf16, weights transpose->bf16, adj->bitmask ----------------
__global__ __launch_bounds__(256) void prep_kernel(
    const float* __restrict__ h, const int* __restrict__ adj,
    const float* __restrict__ Wq, const float* __restrict__ Wk,
    const float* __restrict__ Wv, const float* __restrict__ Wo,
    unsigned short* __restrict__ hbf,
    unsigned short* __restrict__ wqt, unsigned short* __restrict__ wkt,
    unsigned short* __restrict__ wvt, unsigned short* __restrict__ wot,
    unsigned* __restrict__ adjp) {
  int bid = blockIdx.x;
  int tid = threadIdx.x;
  if (bid < 2048) {
    int idx = (bid * 256 + tid) * 4;
    float4 v = *(const float4*)(h + idx);
    ushort4 o;
    o.x = f2bf(v.x); o.y = f2bf(v.y); o.z = f2bf(v.z); o.w = f2bf(v.w);
    *(ushort4*)(hbf + idx) = o;
  } else if (bid < 3072) {
    int t = (bid - 2048) * 256 + tid;
    int w = t >> 16;
    int e = t & 65535;
    int i = e >> 8;      // in-feature
    int o = e & 255;     // out-feature
    const float* W = (w == 0) ? Wq : (w == 1) ? Wk : (w == 2) ? Wv : Wo;
    unsigned short* Wt = (w == 0) ? wqt : (w == 1) ? wkt : (w == 2) ? wvt : wot;
    Wt[o * 256 + i] = f2bf(W[i * 256 + o]);
  } else {
    int lane = tid & 63;
    int wid = (bid - 3072) * 4 + (tid >> 6);
    unsigned long long* adjp64 = (unsigned long long*)adjp;
    #pragma unroll
    for (int it = 0; it < 16; ++it) {
      int widx = wid * 16 + it;
      int base = widx * 64 + lane;
      unsigned long long m = __ballot(adj[base] != 0);
      if (lane == 0) adjp64[widx] = m;
    }
  }
}

// ---------------- QKV projection GEMM: [8192,256] x [256,768] ----------------
__global__ __launch_bounds__(256) void qkv_gemm(
    const unsigned short* __restrict__ hbf,
    const unsigned short* __restrict__ wqt, const unsigned short* __restrict__ wkt,
    const unsigned short* __restrict__ wvt,
    unsigned short* __restrict__ qb, unsigned short* __restrict__ kb,
    unsigned short* __restrict__ vtb) {
  int lane = threadIdx.x & 63;
  int wv = threadIdx.x >> 6;
  int g = lane >> 4;
  int c = lane & 15;
  int row16 = blockIdx.x * 64 + wv * 16;
  int colbase = blockIdx.y * 64;
  int which = colbase >> 8;          // 0=Q 1=K 2=V
  int fbase = colbase & 255;
  const unsigned short* wt = (which == 0) ? wqt : (which == 1) ? wkt : wvt;
  int arow = row16 + c;

  f32x4 acc[4];
  #pragma unroll
  for (int cc = 0; cc < 4; ++cc) acc[cc] = (f32x4){0.f, 0.f, 0.f, 0.f};

  for (int k = 0; k < 256; k += 32) {
    short8 a = *(const short8*)(hbf + arow * 256 + k + g * 8);
    #pragma unroll
    for (int cc = 0; cc < 4; ++cc) {
      int col = fbase + cc * 16 + c;
      short8 bfrag = *(const short8*)(wt + col * 256 + k + g * 8);
      acc[cc] = mfma16(a, bfrag, acc[cc]);
    }
  }

  #pragma unroll
  for (int cc = 0; cc < 4; ++cc) {
    #pragma unroll
    for (int r = 0; r < 4; ++r) {
      int row = row16 + g * 4 + r;
      int f = fbase + cc * 16 + c;
      int hh = f >> 6, d = f & 63;
      int bb = row >> 11, n = row & 2047;
      float v = acc[cc][r];
      if (which == 0)
        qb[((bb * H_ + hh) * N_ + n) * D_ + d] = f2bf(v * 0.125f);
      else if (which == 1)
        kb[((bb * H_ + hh) * N_ + n) * D_ + d] = f2bf(v);
      else
        vtb[((bb * H_ + hh) * D_ + d) * N_ + n] = f2bf(v);
    }
  }
}

// ---------------- flash attention with adjacency mask, KV-split x4 ----------------
__global__ __launch_bounds__(256) void attn_kernel(
    const unsigned short* __restrict__ qb, const unsigned short* __restrict__ kb,
    const unsigned short* __restrict__ vtb, const unsigned* __restrict__ adjp,
    unsigned short* __restrict__ Opart, float* __restrict__ ML) {
  __shared__ __align__(16) unsigned short plds[4][32 * 40];
  int lane = threadIdx.x & 63;
  int wv = threadIdx.x >> 6;
  int g = lane >> 4;
  int c = lane & 15;
  int task = blockIdx.x * 4 + wv;     // 0..4095
  int s = task & 3;                   // KV split
  int qt = (task >> 2) & 63;          // Q tile (32 rows)
  int bh = task >> 8;                 // 0..15
  int qbase = qt * 32;
  const unsigned short* Qp = qb + bh * (N_ * D_);
  const unsigned short* Kp = kb + bh * (N_ * D_);
  const unsigned short* Vt = vtb + bh * (D_ * N_);
  unsigned short* myp = plds[wv];

  short8 qf[2][2];
  #pragma unroll
  for (int rt = 0; rt < 2; ++rt)
    #pragma unroll
    for (int dh = 0; dh < 2; ++dh)
      qf[rt][dh] = *(const short8*)(Qp + (qbase + rt * 16 + c) * D_ + dh * 32 + g * 8);

  f32x4 O[2][4];
  float M[2][4], Lsum[2][4];
  #pragma unroll
  for (int rt = 0; rt < 2; ++rt) {
    #pragma unroll
    for (int dt = 0; dt < 4; ++dt) O[rt][dt] = (f32x4){0.f, 0.f, 0.f, 0.f};
    #pragma unroll
    for (int r = 0; r < 4; ++r) { M[rt][r] = -1e9f; Lsum[rt][r] = 0.f; }
  }

  const f32x4 z4 = {0.f, 0.f, 0.f, 0.f};
  int kv0 = s * 512;

  for (int mb = kv0; mb < kv0 + 512; mb += 32) {
    int mw = mb >> 5;
    short8 kf[2][2];
    #pragma unroll
    for (int mt = 0; mt < 2; ++mt)
      #pragma unroll
      for (int dh = 0; dh < 2; ++dh)
        kf[mt][dh] = *(const short8*)(Kp + (mb + mt * 16 + c) * D_ + dh * 32 + g * 8);

    f32x4 S[2][2];
    #pragma unroll
    for (int rt = 0; rt < 2; ++rt)
      #pragma unroll
      for (int mt = 0; mt < 2; ++mt) {
        f32x4 ss = mfma16(qf[rt][0], kf[mt][0], z4);
        S[rt][mt] = mfma16(qf[rt][1], kf[mt][1], ss);
      }

    #pragma unroll
    for (int rt = 0; rt < 2; ++rt) {
      #pragma unroll
      for (int r = 0; r < 4; ++r) {
        int n = qbase + rt * 16 + g * 4 + r;
        unsigned aw = adjp[n * 64 + mw];
        float s0 = ((aw >> c) & 1u) ? S[rt][0][r] : -1e9f;
        float s1 = ((aw >> (c + 16)) & 1u) ? S[rt][1][r] : -1e9f;
        float mx = fmaxf(s0, s1);
        mx = fmaxf(mx, __shfl_xor(mx, 1));
        mx = fmaxf(mx, __shfl_xor(mx, 2));
        mx = fmaxf(mx, __shfl_xor(mx, 4));
        mx = fmaxf(mx, __shfl_xor(mx, 8));
        float Mn = fmaxf(M[rt][r], mx);
        float sc = __expf(M[rt][r] - Mn);
        M[rt][r] = Mn;
        float p0 = __expf(s0 - Mn);
        float p1 = __expf(s1 - Mn);
        // per-lane partial denominator: cross-lane reduce deferred to epilogue
        Lsum[rt][r] = Lsum[rt][r] * sc + p0 + p1;
        #pragma unroll
        for (int dt = 0; dt < 4; ++dt) O[rt][dt][r] *= sc;
        int prow = rt * 16 + g * 4 + r;
        myp[prow * 40 + c] = f2bf(p0);
        myp[prow * 40 + 16 + c] = f2bf(p1);
      }
    }

    short8 pa[2];
    #pragma unroll
    for (int rt = 0; rt < 2; ++rt)
      pa[rt] = *(const short8*)(myp + (rt * 16 + c) * 40 + g * 8);

    #pragma unroll
    for (int dt = 0; dt < 4; ++dt) {
      short8 vf = *(const short8*)(Vt + (dt * 16 + c) * N_ + mb + g * 8);
      #pragma unroll
      for (int rt = 0; rt < 2; ++rt)
        O[rt][dt] = mfma16(pa[rt], vf, O[rt][dt]);
    }
  }

  // epilogue: reduce per-lane L across the 16 c-lanes, store partials
  unsigned short* Ob = Opart + (size_t)task * 2048;
  #pragma unroll
  for (int rt = 0; rt < 2; ++rt) {
    #pragma unroll
    for (int r = 0; r < 4; ++r) {
      float l = Lsum[rt][r];
      l += __shfl_xor(l, 1);
      l += __shfl_xor(l, 2);
      l += __shfl_xor(l, 4);
      l += __shfl_xor(l, 8);
      int row = rt * 16 + g * 4 + r;
      if (c == 0) {
        ML[task * 64 + row * 2] = M[rt][r];
        ML[task * 64 + row * 2 + 1] = l;
      }
      #pragma unroll
      for (int dt = 0; dt < 4; ++dt)
        Ob[row * 64 + dt * 16 + c] = f2bf(O[rt][dt][r]);
    }
  }
}

// ---------------- combine KV-split partials ----------------
__global__ __launch_bounds__(256) void combine_kernel(
    const unsigned short* __restrict__ Opart, const float* __restrict__ ML,
    unsigned short* __restrict__ ao) {
  int t = blockIdx.x * 256 + threadIdx.x;   // 131072 threads
  int dq = t & 3;
  int n = (t >> 2) & 2047;
  int bh = t >> 13;
  int qt = n >> 5, row32 = n & 31;
  int tbase = bh * 256 + qt * 4;

  float Ms[4], Ls[4];
  #pragma unroll
  for (int s = 0; s < 4; ++s) {
    Ms[s] = ML[(tbase + s) * 64 + row32 * 2];
    Ls[s] = ML[(tbase + s) * 64 + row32 * 2 + 1];
  }
  float Mg = fmaxf(fmaxf(Ms[0], Ms[1]), fmaxf(Ms[2], Ms[3]));
  float w[4], Lg = 0.f;
  #pragma unroll
  for (int s = 0; s < 4; ++s) { w[s] = __expf(Ms[s] - Mg); Lg += Ls[s] * w[s]; }
  float inv = 1.0f / Lg;

  float o[16];
  #pragma unroll
  for (int d = 0; d < 16; ++d) o[d] = 0.f;
  #pragma unroll
  for (int s = 0; s < 4; ++s) {
    const unsigned short* p = Opart + (size_t)(tbase + s) * 2048 + row32 * 64 + dq * 16;
    short8 v0 = *(const short8*)(p);
    short8 v1 = *(const short8*)(p + 8);
    #pragma unroll
    for (int d = 0; d < 8; ++d) {
      o[d]     += w[s] * bf2f((unsigned short)v0[d]);
      o[8 + d] += w[s] * bf2f((unsigned short)v1[d]);
    }
  }

  int bb = bh >> 2, hh = bh & 3;
  short8 ob0, ob1;
  #pragma unroll
  for (int d = 0; d < 8; ++d) {
    ob0[d] = (short)f2bf(o[d] * inv);
    ob1[d] = (short)f2bf(o[8 + d] * inv);
  }
  unsigned short* dst = ao + ((size_t)(bb * N_ + n)) * F_ + hh * 64 + dq * 16;
  *(short8*)(dst) = ob0;
  *(short8*)(dst + 8) = ob1;
}

// ---------------- output GEMM + residual + bias ----------------
__global__ __launch_bounds__(256) void out_gemm(
    const unsigned short* __restrict__ ao, const unsigned short* __restrict__ wot,
    const float* __restrict__ h, const float* __restrict__ bo,
    float* __restrict__ out) {
  int lane = threadIdx.x & 63;
  int wv = threadIdx.x >> 6;
  int g = lane >> 4;
  int c = lane & 15;
  int row16 = blockIdx.x * 64 + wv * 16;
  int colb = blockIdx.y * 64;
  int arow = row16 + c;

  f32x4 acc[4];
  #pragma unroll
  for (int cc = 0; cc < 4; ++cc) acc[cc] = (f32x4){0.f, 0.f, 0.f, 0.f};

  for (int k = 0; k < 256; k += 32) {
    short8 a = *(const short8*)(ao + arow * 256 + k + g * 8);
    #pragma unroll
    for (int cc = 0; cc < 4; ++cc) {
      int col = colb + cc * 16 + c;
      short8 bfrag = *(const short8*)(wot + col * 256 + k + g * 8);
      acc[cc] = mfma16(a, bfrag, acc[cc]);
    }
  }

  #pragma unroll
  for (int cc = 0; cc < 4; ++cc) {
    #pragma unroll
    for (int r = 0; r < 4; ++r) {
      int row = row16 + g * 4 + r;
      int col = colb + cc * 16 + c;
      out[row * 256 + col] = h[row * 256 + col] + bo[col] + acc[cc][r];
    }
  }
}

extern "C" void kernel_launch(void* const* d_in, const int* in_sizes, int n_in,
                              void* d_out, int out_size, void* d_ws, size_t ws_size,
                              hipStream_t stream) {
  (void)in_sizes; (void)n_in; (void)out_size; (void)ws_size;
  const float* h  = (const float*)d_in[0];
  const int* adj  = (const int*)d_in[1];
  const float* Wq = (const float*)d_in[2];
  const float* Wk = (const float*)d_in[3];
  const float* Wv = (const float*)d_in[4];
  const float* Wo = (const float*)d_in[5];
  const float* bo = (const float*)d_in[6];
  float* out = (float*)d_out;

  char* ws = (char*)d_ws;
  unsigned short* hbf = (unsigned short*)(ws + 0);          // 4 MB
  unsigned short* wqt = (unsigned short*)(ws + 4194304);    // 128 KB
  unsigned short* wkt = (unsigned short*)(ws + 4325376);    // 128 KB
  unsigned short* wvt = (unsigned short*)(ws + 4456448);    // 128 KB
  unsigned short* wot = (unsigned short*)(ws + 4587520);    // 128 KB
  unsigned*       adjp = (unsigned*)(ws + 4718592);         // 512 KB
  unsigned short* qb  = (unsigned short*)(ws + 5242880);    // 4 MB
  unsigned short* kb  = (unsigned short*)(ws + 9437184);    // 4 MB
  unsigned short* vtb = (unsigned short*)(ws + 13631488);   // 4 MB
  unsigned short* ao  = (unsigned short*)(ws + 17825792);   // 4 MB
  unsigned short* Opart = (unsigned short*)(ws + 22020096); // 16 MB
  float*          ML  = (float*)(ws + 38797312);            // 1 MB (end ~40 MB)

  prep_kernel<<<4096, 256, 0, stream>>>(h, adj, Wq, Wk, Wv, Wo,
                                        hbf, wqt, wkt, wvt, wot, adjp);
  qkv_gemm<<<dim3(128, 12), 256, 0, stream>>>(hbf, wqt, wkt, wvt, qb, kb, vtb);
  attn_kernel<<<1024, 256, 0, stream>>>(qb, kb, vtb, adjp, Opart, ML);
  combine_kernel<<<512, 256, 0, stream>>>(Opart, ML, ao);
  out_gemm<<<dim3(128, 4), 256, 0, stream>>>(ao, wot, h, bo, out);
}

// Round 4
// 210.044 us; speedup vs baseline: 1.2094x; 1.0025x over previous
//
#include <hip/hip_runtime.h>
#include <hip/hip_bf16.h>

#define B_ 4
#define N_ 2048
#define F_ 256
#define H_ 4
#define D_ 64

typedef __attribute__((ext_vector_type(8))) short short8;
typedef __attribute__((ext_vector_type(4))) float f32x4;

__device__ __forceinline__ unsigned short f2bf(float x) {
  unsigned u = __builtin_bit_cast(unsigned, x);
  u = (u + 0x7fffu + ((u >> 16) & 1u)) >> 16;
  return (unsigned short)u;
}

__device__ __forceinline__ float bf2f(unsigned short x) {
  unsigned u = ((unsigned)x) << 16;
  return __builtin_bit_cast(float, u);
}

__device__ __forceinline__ f32x4 mfma16(short8 a, short8 b, f32x4 c) {
  return __builtin_amdgcn_mfma_f32_16x16x32_bf16(a, b, c, 0, 0, 0);
}

// Q pre-scale: 1/sqrt(64) * log2(e)  -> lets attn use raw v_exp_f32 (exp2)
#define QSCALE 0.1803368801111204f

// ---------------- prep: h->bf16, weights transpose->bf16, adj->bitmask ----------------
__global__ __launch_bounds__(256) void prep_kernel(
    const float* __restrict__ h, const int* __restrict__ adj,
    const float* __restrict__ Wq, const float* __restrict__ Wk,
    const float* __restrict__ Wv, const float* __restrict__ Wo,
    unsigned short* __restrict__ hbf,
    unsigned short* __restrict__ wqt, unsigned short* __restrict__ wkt,
    unsigned short* __restrict__ wvt, unsigned short* __restrict__ wot,
    unsigned* __restrict__ adjp) {
  int bid = blockIdx.x;
  int tid = threadIdx.x;
  if (bid < 2048) {
    int idx = (bid * 256 + tid) * 4;
    float4 v = *(const float4*)(h + idx);
    ushort4 o;
    o.x = f2bf(v.x); o.y = f2bf(v.y); o.z = f2bf(v.z); o.w = f2bf(v.w);
    *(ushort4*)(hbf + idx) = o;
  } else if (bid < 3072) {
    int t = (bid - 2048) * 256 + tid;
    int w = t >> 16;
    int e = t & 65535;
    int i = e >> 8;      // in-feature
    int o = e & 255;     // out-feature
    const float* W = (w == 0) ? Wq : (w == 1) ? Wk : (w == 2) ? Wv : Wo;
    unsigned short* Wt = (w == 0) ? wqt : (w == 1) ? wkt : (w == 2) ? wvt : wot;
    Wt[o * 256 + i] = f2bf(W[i * 256 + o]);
  } else {
    int lane = tid & 63;
    int wid = (bid - 3072) * 4 + (tid >> 6);
    unsigned long long* adjp64 = (unsigned long long*)adjp;
    #pragma unroll
    for (int it = 0; it < 16; ++it) {
      int widx = wid * 16 + it;
      int base = widx * 64 + lane;
      unsigned long long m = __ballot(adj[base] != 0);
      if (lane == 0) adjp64[widx] = m;
    }
  }
}

// ---------------- QKV projection GEMM: [8192,256] x [256,768], 64x64 per wave ----------------
__global__ __launch_bounds__(256) void qkv_gemm(
    const unsigned short* __restrict__ hbf,
    const unsigned short* __restrict__ wqt, const unsigned short* __restrict__ wkt,
    const unsigned short* __restrict__ wvt,
    unsigned short* __restrict__ qb, unsigned short* __restrict__ kb,
    unsigned short* __restrict__ vtb) {
  int lane = threadIdx.x & 63;
  int wv = threadIdx.x >> 6;
  int g = lane >> 4;
  int c = lane & 15;
  int row64 = blockIdx.x * 256 + wv * 64;
  int colbase = blockIdx.y * 64;
  int which = colbase >> 8;          // 0=Q 1=K 2=V
  int fbase = colbase & 255;
  const unsigned short* wt = (which == 0) ? wqt : (which == 1) ? wkt : wvt;

  f32x4 acc[4][4];
  #pragma unroll
  for (int rt = 0; rt < 4; ++rt)
    #pragma unroll
    for (int cc = 0; cc < 4; ++cc) acc[rt][cc] = (f32x4){0.f, 0.f, 0.f, 0.f};

  for (int k = 0; k < 256; k += 32) {
    short8 a[4], b[4];
    #pragma unroll
    for (int rt = 0; rt < 4; ++rt)
      a[rt] = *(const short8*)(hbf + (row64 + rt * 16 + c) * 256 + k + g * 8);
    #pragma unroll
    for (int cc = 0; cc < 4; ++cc)
      b[cc] = *(const short8*)(wt + (fbase + cc * 16 + c) * 256 + k + g * 8);
    #pragma unroll
    for (int rt = 0; rt < 4; ++rt)
      #pragma unroll
      for (int cc = 0; cc < 4; ++cc)
        acc[rt][cc] = mfma16(a[rt], b[cc], acc[rt][cc]);
  }

  #pragma unroll
  for (int rt = 0; rt < 4; ++rt) {
    #pragma unroll
    for (int cc = 0; cc < 4; ++cc) {
      #pragma unroll
      for (int r = 0; r < 4; ++r) {
        int row = row64 + rt * 16 + g * 4 + r;
        int f = fbase + cc * 16 + c;
        int hh = f >> 6, d = f & 63;
        int bb = row >> 11, n = row & 2047;
        float v = acc[rt][cc][r];
        if (which == 0)
          qb[((bb * H_ + hh) * N_ + n) * D_ + d] = f2bf(v * QSCALE);
        else if (which == 1)
          kb[((bb * H_ + hh) * N_ + n) * D_ + d] = f2bf(v);
        else
          vtb[((bb * H_ + hh) * D_ + d) * N_ + n] = f2bf(v);
      }
    }
  }
}

// ---------------- flash attention, no-max softmax, KV-split x4 ----------------
__global__ __launch_bounds__(256) void attn_kernel(
    const unsigned short* __restrict__ qb, const unsigned short* __restrict__ kb,
    const unsigned short* __restrict__ vtb, const unsigned* __restrict__ adjp,
    unsigned short* __restrict__ Opart, float* __restrict__ Lp) {
  __shared__ __align__(16) unsigned short plds[4][32 * 40];
  int lane = threadIdx.x & 63;
  int wv = threadIdx.x >> 6;
  int g = lane >> 4;
  int c = lane & 15;
  int task = blockIdx.x * 4 + wv;     // 0..4095
  int s = task & 3;                   // KV split
  int qt = (task >> 2) & 63;          // Q tile (32 rows)
  int bh = task >> 8;                 // 0..15
  int qbase = qt * 32;
  const unsigned short* Qp = qb + bh * (N_ * D_);
  const unsigned short* Kp = kb + bh * (N_ * D_);
  const unsigned short* Vt = vtb + bh * (D_ * N_);
  unsigned short* myp = plds[wv];

  short8 qf[2][2];
  #pragma unroll
  for (int rt = 0; rt < 2; ++rt)
    #pragma unroll
    for (int dh = 0; dh < 2; ++dh)
      qf[rt][dh] = *(const short8*)(Qp + (qbase + rt * 16 + c) * D_ + dh * 32 + g * 8);

  f32x4 O[2][4];
  float Lsum[2][4];
  #pragma unroll
  for (int rt = 0; rt < 2; ++rt) {
    #pragma unroll
    for (int dt = 0; dt < 4; ++dt) O[rt][dt] = (f32x4){0.f, 0.f, 0.f, 0.f};
    #pragma unroll
    for (int r = 0; r < 4; ++r) Lsum[rt][r] = 0.f;
  }

  const f32x4 z4 = {0.f, 0.f, 0.f, 0.f};
  int kv0 = s * 512;

  for (int mb = kv0; mb < kv0 + 512; mb += 32) {
    int mw = mb >> 5;
    short8 kf[2][2];
    #pragma unroll
    for (int mt = 0; mt < 2; ++mt)
      #pragma unroll
      for (int dh = 0; dh < 2; ++dh)
        kf[mt][dh] = *(const short8*)(Kp + (mb + mt * 16 + c) * D_ + dh * 32 + g * 8);

    f32x4 S[2][2];
    #pragma unroll
    for (int rt = 0; rt < 2; ++rt)
      #pragma unroll
      for (int mt = 0; mt < 2; ++mt) {
        f32x4 ss = mfma16(qf[rt][0], kf[mt][0], z4);
        S[rt][mt] = mfma16(qf[rt][1], kf[mt][1], ss);
      }

    #pragma unroll
    for (int rt = 0; rt < 2; ++rt) {
      #pragma unroll
      for (int r = 0; r < 4; ++r) {
        int n = qbase + rt * 16 + g * 4 + r;
        unsigned aw = adjp[n * 64 + mw];
        // Q carries 1/sqrt(D)*log2(e): p = 2^S, masked -> 0.
        float e0 = __builtin_amdgcn_exp2f(S[rt][0][r]);
        float e1 = __builtin_amdgcn_exp2f(S[rt][1][r]);
        float p0 = ((aw >> c) & 1u) ? e0 : 0.f;
        float p1 = ((aw >> (c + 16)) & 1u) ? e1 : 0.f;
        Lsum[rt][r] += p0 + p1;
        unsigned pr;
        asm("v_cvt_pk_bf16_f32 %0, %1, %2" : "=v"(pr) : "v"(p0), "v"(p1));
        int prow = rt * 16 + g * 4 + r;
        myp[prow * 40 + c] = (unsigned short)pr;
        myp[prow * 40 + 16 + c] = (unsigned short)(pr >> 16);
      }
    }

    short8 pa[2];
    #pragma unroll
    for (int rt = 0; rt < 2; ++rt)
      pa[rt] = *(const short8*)(myp + (rt * 16 + c) * 40 + g * 8);

    #pragma unroll
    for (int dt = 0; dt < 4; ++dt) {
      short8 vf = *(const short8*)(Vt + (dt * 16 + c) * N_ + mb + g * 8);
      #pragma unroll
      for (int rt = 0; rt < 2; ++rt)
        O[rt][dt] = mfma16(pa[rt], vf, O[rt][dt]);
    }
  }

  // epilogue: reduce per-lane L across the 16 c-lanes, store partials
  unsigned short* Ob = Opart + (size_t)task * 2048;
  #pragma unroll
  for (int rt = 0; rt < 2; ++rt) {
    #pragma unroll
    for (int r = 0; r < 4; ++r) {
      float l = Lsum[rt][r];
      l += __shfl_xor(l, 1);
      l += __shfl_xor(l, 2);
      l += __shfl_xor(l, 4);
      l += __shfl_xor(l, 8);
      int row = rt * 16 + g * 4 + r;
      if (c == 0) Lp[task * 32 + row] = l;
      #pragma unroll
      for (int dt = 0; dt < 4; ++dt)
        Ob[row * 64 + dt * 16 + c] = f2bf(O[rt][dt][r]);
    }
  }
}

// ---------------- combine KV-split partials (plain sums) ----------------
__global__ __launch_bounds__(256) void combine_kernel(
    const unsigned short* __restrict__ Opart, const float* __restrict__ Lp,
    unsigned short* __restrict__ ao) {
  int t = blockIdx.x * 256 + threadIdx.x;   // 131072 threads
  int dq = t & 3;
  int n = (t >> 2) & 2047;
  int bh = t >> 13;
  int qt = n >> 5, row32 = n & 31;
  int tbase = bh * 256 + qt * 4;

  float Lg = 0.f;
  #pragma unroll
  for (int s = 0; s < 4; ++s) Lg += Lp[(tbase + s) * 32 + row32];
  float inv = 1.0f / Lg;

  float o[16];
  #pragma unroll
  for (int d = 0; d < 16; ++d) o[d] = 0.f;
  #pragma unroll
  for (int s = 0; s < 4; ++s) {
    const unsigned short* p = Opart + (size_t)(tbase + s) * 2048 + row32 * 64 + dq * 16;
    short8 v0 = *(const short8*)(p);
    short8 v1 = *(const short8*)(p + 8);
    #pragma unroll
    for (int d = 0; d < 8; ++d) {
      o[d]     += bf2f((unsigned short)v0[d]);
      o[8 + d] += bf2f((unsigned short)v1[d]);
    }
  }

  int bb = bh >> 2, hh = bh & 3;
  short8 ob0, ob1;
  #pragma unroll
  for (int d = 0; d < 8; ++d) {
    ob0[d] = (short)f2bf(o[d] * inv);
    ob1[d] = (short)f2bf(o[8 + d] * inv);
  }
  unsigned short* dst = ao + ((size_t)(bb * N_ + n)) * F_ + hh * 64 + dq * 16;
  *(short8*)(dst) = ob0;
  *(short8*)(dst + 8) = ob1;
}

// ---------------- output GEMM + residual + bias, 64x64 per wave ----------------
__global__ __launch_bounds__(256) void out_gemm(
    const unsigned short* __restrict__ ao, const unsigned short* __restrict__ wot,
    const float* __restrict__ h, const float* __restrict__ bo,
    float* __restrict__ out) {
  int lane = threadIdx.x & 63;
  int wv = threadIdx.x >> 6;
  int g = lane >> 4;
  int c = lane & 15;
  int row64 = blockIdx.x * 256 + wv * 64;
  int colb = blockIdx.y * 64;

  f32x4 acc[4][4];
  #pragma unroll
  for (int rt = 0; rt < 4; ++rt)
    #pragma unroll
    for (int cc = 0; cc < 4; ++cc) acc[rt][cc] = (f32x4){0.f, 0.f, 0.f, 0.f};

  for (int k = 0; k < 256; k += 32) {
    short8 a[4], b[4];
    #pragma unroll
    for (int rt = 0; rt < 4; ++rt)
      a[rt] = *(const short8*)(ao + (row64 + rt * 16 + c) * 256 + k + g * 8);
    #pragma unroll
    for (int cc = 0; cc < 4; ++cc)
      b[cc] = *(const short8*)(wot + (colb + cc * 16 + c) * 256 + k + g * 8);
    #pragma unroll
    for (int rt = 0; rt < 4; ++rt)
      #pragma unroll
      for (int cc = 0; cc < 4; ++cc)
        acc[rt][cc] = mfma16(a[rt], b[cc], acc[rt][cc]);
  }

  #pragma unroll
  for (int rt = 0; rt < 4; ++rt) {
    #pragma unroll
    for (int cc = 0; cc < 4; ++cc) {
      #pragma unroll
      for (int r = 0; r < 4; ++r) {
        int row = row64 + rt * 16 + g * 4 + r;
        int col = colb + cc * 16 + c;
        out[row * 256 + col] = h[row * 256 + col] + bo[col] + acc[rt][cc][r];
      }
    }
  }
}

extern "C" void kernel_launch(void* const* d_in, const int* in_sizes, int n_in,
                              void* d_out, int out_size, void* d_ws, size_t ws_size,
                              hipStream_t stream) {
  (void)in_sizes; (void)n_in; (void)out_size; (void)ws_size;
  const float* h  = (const float*)d_in[0];
  const int* adj  = (const int*)d_in[1];
  const float* Wq = (const float*)d_in[2];
  const float* Wk = (const float*)d_in[3];
  const float* Wv = (const float*)d_in[4];
  const float* Wo = (const float*)d_in[5];
  const float* bo = (const float*)d_in[6];
  float* out = (float*)d_out;

  char* ws = (char*)d_ws;
  unsigned short* hbf = (unsigned short*)(ws + 0);          // 4 MB
  unsigned short* wqt = (unsigned short*)(ws + 4194304);    // 128 KB
  unsigned short* wkt = (unsigned short*)(ws + 4325376);    // 128 KB
  unsigned short* wvt = (unsigned short*)(ws + 4456448);    // 128 KB
  unsigned short* wot = (unsigned short*)(ws + 4587520);    // 128 KB
  unsigned*       adjp = (unsigned*)(ws + 4718592);         // 512 KB
  unsigned short* qb  = (unsigned short*)(ws + 5242880);    // 4 MB
  unsigned short* kb  = (unsigned short*)(ws + 9437184);    // 4 MB
  unsigned short* vtb = (unsigned short*)(ws + 13631488);   // 4 MB
  unsigned short* ao  = (unsigned short*)(ws + 17825792);   // 4 MB
  unsigned short* Opart = (unsigned short*)(ws + 22020096); // 16 MB
  float*          Lp  = (float*)(ws + 38797312);            // 512 KB

  prep_kernel<<<4096, 256, 0, stream>>>(h, adj, Wq, Wk, Wv, Wo,
                                        hbf, wqt, wkt, wvt, wot, adjp);
  qkv_gemm<<<dim3(32, 12), 256, 0, stream>>>(hbf, wqt, wkt, wvt, qb, kb, vtb);
  attn_kernel<<<1024, 256, 0, stream>>>(qb, kb, vtb, adjp, Opart, Lp);
  combine_kernel<<<512, 256, 0, stream>>>(Opart, Lp, ao);
  out_gemm<<<dim3(32, 4), 256, 0, stream>>>(ao, wot, h, bo, out);
}

// Round 8
// 199.899 us; speedup vs baseline: 1.2708x; 1.0507x over previous
//
#include <hip/hip_runtime.h>
#include <hip/hip_bf16.h>

#define B_ 4
#define N_ 2048
#define F_ 256
#define H_ 4
#define D_ 64

typedef __attribute__((ext_vector_type(8))) short short8;
typedef __attribute__((ext_vector_type(4))) float f32x4;
typedef __attribute__((ext_vector_type(4))) unsigned u32x4;

__device__ __forceinline__ unsigned short f2bf(float x) {
  unsigned u = __builtin_bit_cast(unsigned, x);
  u = (u + 0x7fffu + ((u >> 16) & 1u)) >> 16;
  return (unsigned short)u;
}

__device__ __forceinline__ float bf2f(unsigned short x) {
  unsigned u = ((unsigned)x) << 16;
  return __builtin_bit_cast(float, u);
}

__device__ __forceinline__ f32x4 mfma16(short8 a, short8 b, f32x4 c) {
  return __builtin_amdgcn_mfma_f32_16x16x32_bf16(a, b, c, 0, 0, 0);
}

// Q pre-scale: 1/sqrt(64) * log2(e)  -> attn uses raw v_exp_f32 (exp2)
#define QSCALE 0.1803368801111204f

// ---------------- prep: h->bf16, weights transpose->bf16, adj->transposed bitmask ----------------
__global__ __launch_bounds__(256) void prep_kernel(
    const float* __restrict__ h, const int* __restrict__ adj,
    const float* __restrict__ Wq, const float* __restrict__ Wk,
    const float* __restrict__ Wv, const float* __restrict__ Wo,
    unsigned short* __restrict__ hbf,
    unsigned short* __restrict__ wqt, unsigned short* __restrict__ wkt,
    unsigned short* __restrict__ wvt, unsigned short* __restrict__ wot,
    unsigned* __restrict__ adjt) {
  int bid = blockIdx.x;
  int tid = threadIdx.x;
  if (bid < 2048) {
    int idx = (bid * 256 + tid) * 4;
    float4 v = *(const float4*)(h + idx);
    ushort4 o;
    o.x = f2bf(v.x); o.y = f2bf(v.y); o.z = f2bf(v.z); o.w = f2bf(v.w);
    *(ushort4*)(hbf + idx) = o;
  } else if (bid < 3072) {
    int t = (bid - 2048) * 256 + tid;
    int w = t >> 16;
    int e = t & 65535;
    int i = e >> 8;      // in-feature
    int o = e & 255;     // out-feature
    const float* W = (w == 0) ? Wq : (w == 1) ? Wk : (w == 2) ? Wv : Wo;
    unsigned short* Wt = (w == 0) ? wqt : (w == 1) ? wkt : (w == 2) ? wvt : wot;
    Wt[o * 256 + i] = f2bf(W[i * 256 + o]);
  } else {
    // adj bit-pack, TRANSPOSED layout: adjt[mw*2048 + n] = 32 column-bits
    // [mw*32, mw*32+32) of row n.
    int lane = tid & 63;
    int wid = (bid - 3072) * 4 + (tid >> 6);   // 0..4095
    #pragma unroll
    for (int it = 0; it < 16; ++it) {
      int widx = wid * 16 + it;                // 0..65535
      int n = widx >> 5;
      int mw64 = widx & 31;
      unsigned long long m = __ballot(adj[widx * 64 + lane] != 0);
      if (lane == 0) {
        adjt[(2 * mw64) * 2048 + n] = (unsigned)m;
        adjt[(2 * mw64 + 1) * 2048 + n] = (unsigned)(m >> 32);
      }
    }
  }
}

// ---------------- QKV projection GEMM: [8192,256] x [256,768], 32x64 per wave ----------------
__global__ __launch_bounds__(256) void qkv_gemm(
    const unsigned short* __restrict__ hbf,
    const unsigned short* __restrict__ wqt, const unsigned short* __restrict__ wkt,
    const unsigned short* __restrict__ wvt,
    unsigned short* __restrict__ qb, unsigned short* __restrict__ kb,
    unsigned short* __restrict__ vtb) {
  int lane = threadIdx.x & 63;
  int wv = threadIdx.x >> 6;
  int g = lane >> 4;
  int c = lane & 15;
  int row32 = blockIdx.x * 128 + wv * 32;
  int colbase = blockIdx.y * 64;
  int which = colbase >> 8;          // 0=Q 1=K 2=V
  int fbase = colbase & 255;
  const unsigned short* wt = (which == 0) ? wqt : (which == 1) ? wkt : wvt;

  f32x4 acc[2][4];
  #pragma unroll
  for (int rt = 0; rt < 2; ++rt)
    #pragma unroll
    for (int cc = 0; cc < 4; ++cc) acc[rt][cc] = (f32x4){0.f, 0.f, 0.f, 0.f};

  for (int k = 0; k < 256; k += 32) {
    short8 a[2], b[4];
    #pragma unroll
    for (int rt = 0; rt < 2; ++rt)
      a[rt] = *(const short8*)(hbf + (row32 + rt * 16 + c) * 256 + k + g * 8);
    #pragma unroll
    for (int cc = 0; cc < 4; ++cc)
      b[cc] = *(const short8*)(wt + (fbase + cc * 16 + c) * 256 + k + g * 8);
    #pragma unroll
    for (int rt = 0; rt < 2; ++rt)
      #pragma unroll
      for (int cc = 0; cc < 4; ++cc)
        acc[rt][cc] = mfma16(a[rt], b[cc], acc[rt][cc]);
  }

  #pragma unroll
  for (int rt = 0; rt < 2; ++rt) {
    #pragma unroll
    for (int cc = 0; cc < 4; ++cc) {
      #pragma unroll
      for (int r = 0; r < 4; ++r) {
        int row = row32 + rt * 16 + g * 4 + r;
        int f = fbase + cc * 16 + c;
        int hh = f >> 6, d = f & 63;
        int bb = row >> 11, n = row & 2047;
        float v = acc[rt][cc][r];
        if (which == 0)
          qb[((bb * H_ + hh) * N_ + n) * D_ + d] = f2bf(v * QSCALE);
        else if (which == 1)
          kb[((bb * H_ + hh) * N_ + n) * D_ + d] = f2bf(v);
        else
          vtb[((bb * H_ + hh) * D_ + d) * N_ + n] = f2bf(v);
      }
    }
  }
}

// ---------------- flash attention: no-max softmax, KV-split x4, XCD-swizzled,
// ---------------- K-prefetch pipeline, double-buffered P-LDS ----------------
__global__ __launch_bounds__(256) void attn_kernel(
    const unsigned short* __restrict__ qb, const unsigned short* __restrict__ kb,
    const unsigned short* __restrict__ vtb, const unsigned* __restrict__ adjt,
    unsigned short* __restrict__ Opart, float* __restrict__ Lp) {
  __shared__ __align__(16) unsigned short plds[4][2][32 * 40];
  int lane = threadIdx.x & 63;
  int wv = threadIdx.x >> 6;
  int g = lane >> 4;
  int c = lane & 15;
  // XCD swizzle: 1024 blocks, 8 XCDs round-robin -> each XCD owns bh pair
  int lb = (blockIdx.x & 7) * 128 + (blockIdx.x >> 3);
  int bh = lb >> 6;
  int qt = lb & 63;
  int s = wv;                          // KV split = wave id (shares Q tile in block)
  int task = bh * 256 + qt * 4 + s;    // layout consumed by combine_kernel
  int qbase = qt * 32;
  const unsigned short* Qp = qb + bh * (N_ * D_);
  const unsigned short* Kp = kb + bh * (N_ * D_);
  const unsigned short* Vt = vtb + bh * (D_ * N_);

  short8 qf[2][2];
  #pragma unroll
  for (int rt = 0; rt < 2; ++rt)
    #pragma unroll
    for (int dh = 0; dh < 2; ++dh)
      qf[rt][dh] = *(const short8*)(Qp + (qbase + rt * 16 + c) * D_ + dh * 32 + g * 8);

  f32x4 O[2][4];
  float Lsum[2][4];
  #pragma unroll
  for (int rt = 0; rt < 2; ++rt) {
    #pragma unroll
    for (int dt = 0; dt < 4; ++dt) O[rt][dt] = (f32x4){0.f, 0.f, 0.f, 0.f};
    #pragma unroll
    for (int r = 0; r < 4; ++r) Lsum[rt][r] = 0.f;
  }

  const f32x4 z4 = {0.f, 0.f, 0.f, 0.f};
  int kv0 = s * 512;

  // prologue: prefetch first tile's K frags
  short8 kfa[2][2], kfb[2][2];
  #pragma unroll
  for (int mt = 0; mt < 2; ++mt)
    #pragma unroll
    for (int dh = 0; dh < 2; ++dh)
      kfa[mt][dh] = *(const short8*)(Kp + (kv0 + mt * 16 + c) * D_ + dh * 32 + g * 8);

  for (int it = 0; it < 16; ++it) {
    int mb = kv0 + it * 32;
    int mw = mb >> 5;
    int nmb = (it == 15) ? kv0 : (mb + 32);   // wrap: prefetch stays in-bounds, unused on last
    // 1) issue next-tile K prefetch (consumed at rotate, after PV -> latency hidden)
    #pragma unroll
    for (int mt = 0; mt < 2; ++mt)
      #pragma unroll
      for (int dh = 0; dh < 2; ++dh)
        kfb[mt][dh] = *(const short8*)(Kp + (nmb + mt * 16 + c) * D_ + dh * 32 + g * 8);
    // 2) issue mask loads for current tile (2 x uint4, transposed layout)
    u32x4 awq[2];
    #pragma unroll
    for (int rt = 0; rt < 2; ++rt)
      awq[rt] = *(const u32x4*)(adjt + mw * 2048 + qbase + rt * 16 + g * 4);

    // 3) QK^T from registers (kfa prefetched -> no wait)
    f32x4 S[2][2];
    #pragma unroll
    for (int rt = 0; rt < 2; ++rt)
      #pragma unroll
      for (int mt = 0; mt < 2; ++mt) {
        f32x4 ss = mfma16(qf[rt][0], kfa[mt][0], z4);
        S[rt][mt] = mfma16(qf[rt][1], kfa[mt][1], ss);
      }

    // 4) masked exp2 softmax (no running max; scores bounded), write P to LDS
    unsigned short* myp = plds[wv][it & 1];
    #pragma unroll
    for (int rt = 0; rt < 2; ++rt) {
      #pragma unroll
      for (int r = 0; r < 4; ++r) {
        unsigned aw = awq[rt][r];
        float e0 = __builtin_amdgcn_exp2f(S[rt][0][r]);
        float e1 = __builtin_amdgcn_exp2f(S[rt][1][r]);
        float p0 = ((aw >> c) & 1u) ? e0 : 0.f;
        float p1 = ((aw >> (c + 16)) & 1u) ? e1 : 0.f;
        Lsum[rt][r] += p0 + p1;
        unsigned pr;
        asm("v_cvt_pk_bf16_f32 %0, %1, %2" : "=v"(pr) : "v"(p0), "v"(p1));
        int prow = rt * 16 + g * 4 + r;
        myp[prow * 40 + c] = (unsigned short)pr;
        myp[prow * 40 + 16 + c] = (unsigned short)(pr >> 16);
      }
    }

    // 5) P back as A-frags; V just-in-time; PV accumulate
    short8 pa[2];
    #pragma unroll
    for (int rt = 0; rt < 2; ++rt)
      pa[rt] = *(const short8*)(myp + (rt * 16 + c) * 40 + g * 8);

    #pragma unroll
    for (int dt = 0; dt < 4; ++dt) {
      short8 vf = *(const short8*)(Vt + (dt * 16 + c) * N_ + mb + g * 8);
      #pragma unroll
      for (int rt = 0; rt < 2; ++rt)
        O[rt][dt] = mfma16(pa[rt], vf, O[rt][dt]);
    }

    // 6) rotate prefetched K
    #pragma unroll
    for (int mt = 0; mt < 2; ++mt)
      #pragma unroll
      for (int dh = 0; dh < 2; ++dh)
        kfa[mt][dh] = kfb[mt][dh];
  }

  // epilogue: reduce per-lane L across the 16 c-lanes, store partials
  unsigned short* Ob = Opart + (size_t)task * 2048;
  #pragma unroll
  for (int rt = 0; rt < 2; ++rt) {
    #pragma unroll
    for (int r = 0; r < 4; ++r) {
      float l = Lsum[rt][r];
      l += __shfl_xor(l, 1);
      l += __shfl_xor(l, 2);
      l += __shfl_xor(l, 4);
      l += __shfl_xor(l, 8);
      int row = rt * 16 + g * 4 + r;
      if (c == 0) Lp[task * 32 + row] = l;
      #pragma unroll
      for (int dt = 0; dt < 4; ++dt)
        Ob[row * 64 + dt * 16 + c] = f2bf(O[rt][dt][r]);
    }
  }
}

// ---------------- combine KV-split partials (plain sums) ----------------
__global__ __launch_bounds__(256) void combine_kernel(
    const unsigned short* __restrict__ Opart, const float* __restrict__ Lp,
    unsigned short* __restrict__ ao) {
  int t = blockIdx.x * 256 + threadIdx.x;   // 131072 threads
  int dq = t & 3;
  int n = (t >> 2) & 2047;
  int bh = t >> 13;
  int qt = n >> 5, row32 = n & 31;
  int tbase = bh * 256 + qt * 4;

  float Lg = 0.f;
  #pragma unroll
  for (int s = 0; s < 4; ++s) Lg += Lp[(tbase + s) * 32 + row32];
  float inv = 1.0f / Lg;

  float o[16];
  #pragma unroll
  for (int d = 0; d < 16; ++d) o[d] = 0.f;
  #pragma unroll
  for (int s = 0; s < 4; ++s) {
    const unsigned short* p = Opart + (size_t)(tbase + s) * 2048 + row32 * 64 + dq * 16;
    short8 v0 = *(const short8*)(p);
    short8 v1 = *(const short8*)(p + 8);
    #pragma unroll
    for (int d = 0; d < 8; ++d) {
      o[d]     += bf2f((unsigned short)v0[d]);
      o[8 + d] += bf2f((unsigned short)v1[d]);
    }
  }

  int bb = bh >> 2, hh = bh & 3;
  short8 ob0, ob1;
  #pragma unroll
  for (int d = 0; d < 8; ++d) {
    ob0[d] = (short)f2bf(o[d] * inv);
    ob1[d] = (short)f2bf(o[8 + d] * inv);
  }
  unsigned short* dst = ao + ((size_t)(bb * N_ + n)) * F_ + hh * 64 + dq * 16;
  *(short8*)(dst) = ob0;
  *(short8*)(dst + 8) = ob1;
}

// ---------------- output GEMM + residual + bias, 16x64 per wave ----------------
__global__ __launch_bounds__(256) void out_gemm(
    const unsigned short* __restrict__ ao, const unsigned short* __restrict__ wot,
    const float* __restrict__ h, const float* __restrict__ bo,
    float* __restrict__ out) {
  int lane = threadIdx.x & 63;
  int wv = threadIdx.x >> 6;
  int g = lane >> 4;
  int c = lane & 15;
  int row16 = blockIdx.x * 64 + wv * 16;
  int colb = blockIdx.y * 64;
  int arow = row16 + c;

  f32x4 acc[4];
  #pragma unroll
  for (int cc = 0; cc < 4; ++cc) acc[cc] = (f32x4){0.f, 0.f, 0.f, 0.f};

  for (int k = 0; k < 256; k += 32) {
    short8 a = *(const short8*)(ao + arow * 256 + k + g * 8);
    #pragma unroll
    for (int cc = 0; cc < 4; ++cc) {
      short8 bfrag = *(const short8*)(wot + (colb + cc * 16 + c) * 256 + k + g * 8);
      acc[cc] = mfma16(a, bfrag, acc[cc]);
    }
  }

  #pragma unroll
  for (int cc = 0; cc < 4; ++cc) {
    #pragma unroll
    for (int r = 0; r < 4; ++r) {
      int row = row16 + g * 4 + r;
      int col = colb + cc * 16 + c;
      out[row * 256 + col] = h[row * 256 + col] + bo[col] + acc[cc][r];
    }
  }
}

extern "C" void kernel_launch(void* const* d_in, const int* in_sizes, int n_in,
                              void* d_out, int out_size, void* d_ws, size_t ws_size,
                              hipStream_t stream) {
  (void)in_sizes; (void)n_in; (void)out_size; (void)ws_size;
  const float* h  = (const float*)d_in[0];
  const int* adj  = (const int*)d_in[1];
  const float* Wq = (const float*)d_in[2];
  const float* Wk = (const float*)d_in[3];
  const float* Wv = (const float*)d_in[4];
  const float* Wo = (const float*)d_in[5];
  const float* bo = (const float*)d_in[6];
  float* out = (float*)d_out;

  char* ws = (char*)d_ws;
  unsigned short* hbf = (unsigned short*)(ws + 0);          // 4 MB
  unsigned short* wqt = (unsigned short*)(ws + 4194304);    // 128 KB
  unsigned short* wkt = (unsigned short*)(ws + 4325376);    // 128 KB
  unsigned short* wvt = (unsigned short*)(ws + 4456448);    // 128 KB
  unsigned short* wot = (unsigned short*)(ws + 4587520);    // 128 KB
  unsigned*       adjt = (unsigned*)(ws + 4718592);         // 512 KB (transposed bitmask)
  unsigned short* qb  = (unsigned short*)(ws + 5242880);    // 4 MB
  unsigned short* kb  = (unsigned short*)(ws + 9437184);    // 4 MB
  unsigned short* vtb = (unsigned short*)(ws + 13631488);   // 4 MB
  unsigned short* ao  = (unsigned short*)(ws + 17825792);   // 4 MB
  unsigned short* Opart = (unsigned short*)(ws + 22020096); // 16 MB
  float*          Lp  = (float*)(ws + 38797312);            // 512 KB

  prep_kernel<<<4096, 256, 0, stream>>>(h, adj, Wq, Wk, Wv, Wo,
                                        hbf, wqt, wkt, wvt, wot, adjt);
  qkv_gemm<<<dim3(64, 12), 256, 0, stream>>>(hbf, wqt, wkt, wvt, qb, kb, vtb);
  attn_kernel<<<1024, 256, 0, stream>>>(qb, kb, vtb, adjt, Opart, Lp);
  combine_kernel<<<512, 256, 0, stream>>>(Opart, Lp, ao);
  out_gemm<<<dim3(128, 4), 256, 0, stream>>>(ao, wot, h, bo, out);
}